// Round 1
// baseline (1592.614 us; speedup 1.0000x reference)
//
#include <hip/hip_runtime.h>
#include <math.h>

// Problem constants (fixed by reference file)
#define BB 8
#define CC 512
#define HWN 4096   // H_*W_ = 64*64

// ---------------------------------------------------------------------------
// Generic tiled fp32 GEMM.
//   C[m,n] = alpha * ( sum_k opA(A)[m,k] * opB(B)[k,n] + bias_term )
// TA=0: A is [M,K] row-major (ld=K).  TA=1: A is [K,M] row-major (ld=M).
// TB=0: B is [K,N] row-major (ld=N).  TB=1: B is [N,K] row-major (ld=K).
// BIASMODE: 0 none, 1 bias[m], 2 bias[n]  (bias added BEFORE alpha scaling)
// Batched via blockIdx.z with element strides sA/sB/sC.
// Tiles: 64x64 block tile, BK=16, 256 threads, 4x4 micro-tile per thread.
// All problem dims here are multiples of 64/16 -> no bounds checks.
// ---------------------------------------------------------------------------
template <int TA, int TB, int BIASMODE>
__global__ __launch_bounds__(256) void gemm_tiled(
    const float* __restrict__ Ag, const float* __restrict__ Bg,
    const float* __restrict__ bias, float* __restrict__ Cg,
    int M, int N, int K, long sA, long sB, long sC, float alpha) {
  __shared__ float As[16][64];
  __shared__ float Bs[16][64];

  const int tid = threadIdx.x;
  const int n0 = blockIdx.x * 64;
  const int m0 = blockIdx.y * 64;
  Ag += (long)blockIdx.z * sA;
  Bg += (long)blockIdx.z * sB;
  Cg += (long)blockIdx.z * sC;

  const int tx = tid & 15;   // n micro index
  const int ty = tid >> 4;   // m micro index

  float acc[4][4] = {};

  for (int k0 = 0; k0 < K; k0 += 16) {
    __syncthreads();  // protect previous iteration's reads before overwrite
#pragma unroll
    for (int i = 0; i < 4; i++) {
      const int idx = tid + i * 256;  // 0..1023 covers the 64x16 tile
      if (TA == 0) {
        const int m = idx >> 4, k = idx & 15;   // k fast -> coalesced global
        As[k][m] = Ag[(long)(m0 + m) * K + (k0 + k)];
      } else {
        const int k = idx >> 6, m = idx & 63;   // m fast -> coalesced global
        As[k][m] = Ag[(long)(k0 + k) * M + (m0 + m)];
      }
      if (TB == 0) {
        const int k = idx >> 6, n = idx & 63;   // n fast -> coalesced global
        Bs[k][n] = Bg[(long)(k0 + k) * N + (n0 + n)];
      } else {
        const int n = idx >> 4, k = idx & 15;   // k fast -> coalesced global
        Bs[k][n] = Bg[(long)(n0 + n) * K + (k0 + k)];
      }
    }
    __syncthreads();

#pragma unroll
    for (int k = 0; k < 16; k++) {
      const float4 a4 = *reinterpret_cast<const float4*>(&As[k][ty * 4]);
      const float4 b4 = *reinterpret_cast<const float4*>(&Bs[k][tx * 4]);
      const float av_[4] = {a4.x, a4.y, a4.z, a4.w};
      const float bv_[4] = {b4.x, b4.y, b4.z, b4.w};
#pragma unroll
      for (int i = 0; i < 4; i++)
#pragma unroll
        for (int j = 0; j < 4; j++) acc[i][j] += av_[i] * bv_[j];
    }
  }

#pragma unroll
  for (int i = 0; i < 4; i++) {
    const int m = m0 + ty * 4 + i;
#pragma unroll
    for (int j = 0; j < 4; j++) {
      const int n = n0 + tx * 4 + j;
      float v = acc[i][j];
      if (BIASMODE == 1) v += bias[m];
      else if (BIASMODE == 2) v += bias[n];
      Cg[(long)m * N + n] = v * alpha;
    }
  }
}

// ---------------------------------------------------------------------------
// In-place numerically-stable softmax over rows of length 4096.
// One 256-thread block per row; each thread holds 16 values in registers
// (4x float4) -> single global read + single global write.
// ---------------------------------------------------------------------------
__global__ __launch_bounds__(256) void softmax_rows(float* __restrict__ buf) {
  const long row = blockIdx.x;
  float4* p = reinterpret_cast<float4*>(buf + row * (long)HWN);
  const int tid = threadIdx.x;

  float4 v[4];
  float vmax = -3.0e38f;
#pragma unroll
  for (int i = 0; i < 4; i++) {
    v[i] = p[tid + i * 256];
    vmax = fmaxf(vmax, fmaxf(fmaxf(v[i].x, v[i].y), fmaxf(v[i].z, v[i].w)));
  }
#pragma unroll
  for (int off = 32; off > 0; off >>= 1)
    vmax = fmaxf(vmax, __shfl_xor(vmax, off, 64));

  __shared__ float red[4];
  const int wid = tid >> 6;
  if ((tid & 63) == 0) red[wid] = vmax;
  __syncthreads();
  vmax = fmaxf(fmaxf(red[0], red[1]), fmaxf(red[2], red[3]));
  __syncthreads();  // red[] reused below

  float s = 0.f;
#pragma unroll
  for (int i = 0; i < 4; i++) {
    v[i].x = expf(v[i].x - vmax);
    v[i].y = expf(v[i].y - vmax);
    v[i].z = expf(v[i].z - vmax);
    v[i].w = expf(v[i].w - vmax);
    s += (v[i].x + v[i].y) + (v[i].z + v[i].w);
  }
#pragma unroll
  for (int off = 32; off > 0; off >>= 1) s += __shfl_xor(s, off, 64);
  if ((tid & 63) == 0) red[wid] = s;
  __syncthreads();
  s = (red[0] + red[1]) + (red[2] + red[3]);

  const float inv = 1.0f / s;
#pragma unroll
  for (int i = 0; i < 4; i++) {
    v[i].x *= inv; v[i].y *= inv; v[i].z *= inv; v[i].w *= inv;
    p[tid + i * 256] = v[i];
  }
}

// ---------------------------------------------------------------------------
// Plan (per call):
//  1. Bm logits = wB @ x + bB            -> d_out   [B,C,HW]   (scratch use)
//  2. softmax rows of d_out (in place)   -> Bm
//  3. M = Bm @ x^T                       -> ws.gM   [B,C,C]
//  4. gd = (M @ wA^T + bA) / HW          -> ws.gGd  [B,C,C]
//     (valid because softmax rows sum to 1: avoids materializing A)
//  5. av logits = wV @ x + bV            -> ws.gAv  [B,C,HW]
//  6. softmax rows of gAv                -> av
//  7. out = gd^T @ av                    -> d_out   [B,C,HW]
// ws usage: 64 MiB (gAv) + 8 MiB (gM) + 8 MiB (gGd) = 80 MiB.
// ---------------------------------------------------------------------------
extern "C" void kernel_launch(void* const* d_in, const int* in_sizes, int n_in,
                              void* d_out, int out_size, void* d_ws,
                              size_t ws_size, hipStream_t stream) {
  const float* x  = (const float*)d_in[0];
  const float* wA = (const float*)d_in[1];
  const float* bA = (const float*)d_in[2];
  const float* wB = (const float*)d_in[3];
  const float* bB = (const float*)d_in[4];
  const float* wV = (const float*)d_in[5];
  const float* bV = (const float*)d_in[6];
  float* out = (float*)d_out;

  float* gAv = (float*)d_ws;                       // B*C*HW floats
  float* gM  = gAv + (size_t)BB * CC * HWN;        // B*C*C floats
  float* gGd = gM  + (size_t)BB * CC * CC;         // B*C*C floats

  const long sBC_HW = (long)CC * HWN;  // per-batch stride of [C,HW] tensors
  const long sCC    = (long)CC * CC;   // per-batch stride of [C,C] tensors
  const dim3 blk(256);

  // 1. Bm logits -> d_out : A=wB [C,C] (N), B=x [C,HW] (N), bias[m]
  gemm_tiled<0, 0, 1><<<dim3(HWN / 64, CC / 64, BB), blk, 0, stream>>>(
      wB, x, bB, out, CC, HWN, CC, 0, sBC_HW, sBC_HW, 1.0f);
  // 2. softmax
  softmax_rows<<<dim3(BB * CC), blk, 0, stream>>>(out);
  // 3. M = Bm @ x^T : A=Bm [C,HW] (N), B=x [C,HW] (T), K=HW
  gemm_tiled<0, 1, 0><<<dim3(CC / 64, CC / 64, BB), blk, 0, stream>>>(
      out, x, nullptr, gM, CC, CC, HWN, sBC_HW, sBC_HW, sCC, 1.0f);
  // 4. gd = (M @ wA^T + bA[n]) / HW : A=M [C,C] (N), B=wA [C,C] (T)
  gemm_tiled<0, 1, 2><<<dim3(CC / 64, CC / 64, BB), blk, 0, stream>>>(
      gM, wA, bA, gGd, CC, CC, CC, sCC, 0, sCC, 1.0f / (float)HWN);
  // 5. av logits -> gAv
  gemm_tiled<0, 0, 1><<<dim3(HWN / 64, CC / 64, BB), blk, 0, stream>>>(
      wV, x, bV, gAv, CC, HWN, CC, 0, sBC_HW, sBC_HW, 1.0f);
  // 6. softmax
  softmax_rows<<<dim3(BB * CC), blk, 0, stream>>>(gAv);
  // 7. out = gd^T @ av : A=gd [K=i,M=j] (T, ld=M=C), B=av [C,HW] (N)
  gemm_tiled<1, 0, 0><<<dim3(HWN / 64, CC / 64, BB), blk, 0, stream>>>(
      gGd, gAv, nullptr, out, CC, HWN, CC, sCC, sBC_HW, sBC_HW, 1.0f);
}

// Round 2
// 383.088 us; speedup vs baseline: 4.1573x; 4.1573x over previous
//
#include <hip/hip_runtime.h>
#include <math.h>

#define BB 8
#define CC 512
#define HWN 4096

typedef __bf16 bf16x8 __attribute__((ext_vector_type(8)));
typedef __bf16 bf16x4 __attribute__((ext_vector_type(4)));
typedef float f32x4 __attribute__((ext_vector_type(4)));

// ---------------------------------------------------------------------------
// MFMA bf16 GEMM, "BT" canonical form:
//   C[m,n] = alpha * ( sum_k A[m,k]*B[n,k] + bias_term )
// A: [M,K] row-major bf16 (k contiguous). B: [N,K] row-major bf16 (k contig).
// C: [M,N] row-major, OUT_T (float or __bf16).
// BIASMODE: 0 none, 1 bias[m] (fp32, added before alpha).
// Tiles: 128x128 block, BK=32, 256 threads = 4 waves (2x2), each wave 64x64
// via 4x4 grid of 16x16x32 MFMAs. Dims must be multiples of 128/32.
// Fragment layouts (HW-verified, guide §3):
//   A/B operand: lane l holds [row/col = l&15][k = (l>>4)*8 + j], j=0..7
//   C/D:         lane l, reg r -> row = (l>>4)*4 + r, col = l&15
// ---------------------------------------------------------------------------
template <int BIASMODE, typename OUT_T>
__global__ __launch_bounds__(256) void gemm_mfma_bt(
    const __bf16* __restrict__ Ag, const __bf16* __restrict__ Bg,
    const float* __restrict__ bias, OUT_T* __restrict__ Cg,
    int M, int N, int K, long sA, long sB, long sC, float alpha) {
  __shared__ __bf16 As[128][40];  // +8 pad: 80B row pitch -> 2-way max (free)
  __shared__ __bf16 Bs[128][40];

  const int tid = threadIdx.x;
  const int n0 = blockIdx.x * 128;
  const int m0 = blockIdx.y * 128;
  Ag += (long)blockIdx.z * sA;
  Bg += (long)blockIdx.z * sB;
  Cg += (long)blockIdx.z * sC;

  const int lane = tid & 63;
  const int wv = tid >> 6;        // wave id 0..3
  const int wr = wv >> 1;         // wave row (m) 0..1
  const int wc = wv & 1;          // wave col (n) 0..1
  const int l15 = lane & 15;
  const int quad = lane >> 4;

  f32x4 acc[4][4] = {};

  for (int k0 = 0; k0 < K; k0 += 32) {
    __syncthreads();
#pragma unroll
    for (int i = 0; i < 2; i++) {
      const int idx = tid + i * 256;          // 0..511
      const int row = idx >> 2, seg = idx & 3;  // 4 x 16B segs per 32-k row
      *(bf16x8*)&As[row][seg * 8] =
          *(const bf16x8*)&Ag[(long)(m0 + row) * K + k0 + seg * 8];
      *(bf16x8*)&Bs[row][seg * 8] =
          *(const bf16x8*)&Bg[(long)(n0 + row) * K + k0 + seg * 8];
    }
    __syncthreads();

    bf16x8 af[4], bfr[4];
#pragma unroll
    for (int t = 0; t < 4; t++) {
      af[t]  = *(const bf16x8*)&As[wr * 64 + t * 16 + l15][quad * 8];
      bfr[t] = *(const bf16x8*)&Bs[wc * 64 + t * 16 + l15][quad * 8];
    }
#pragma unroll
    for (int ti = 0; ti < 4; ti++)
#pragma unroll
      for (int tj = 0; tj < 4; tj++)
        acc[ti][tj] = __builtin_amdgcn_mfma_f32_16x16x32_bf16(
            af[ti], bfr[tj], acc[ti][tj], 0, 0, 0);
  }

#pragma unroll
  for (int ti = 0; ti < 4; ti++) {
#pragma unroll
    for (int tj = 0; tj < 4; tj++) {
#pragma unroll
      for (int r = 0; r < 4; r++) {
        const int m = m0 + wr * 64 + ti * 16 + quad * 4 + r;
        const int n = n0 + wc * 64 + tj * 16 + l15;
        float v = acc[ti][tj][r];
        if (BIASMODE == 1) v += bias[m];
        Cg[(long)m * N + n] = (OUT_T)(v * alpha);
      }
    }
  }
}

// ---------------------------------------------------------------------------
// Row softmax over length-4096 rows: fp32 in -> bf16 out. One block per row.
// ---------------------------------------------------------------------------
__global__ __launch_bounds__(256) void softmax_rows_bf16(
    const float* __restrict__ in, __bf16* __restrict__ out) {
  const long row = blockIdx.x;
  const float4* p = reinterpret_cast<const float4*>(in + row * (long)HWN);
  bf16x4* q = reinterpret_cast<bf16x4*>(out + row * (long)HWN);
  const int tid = threadIdx.x;

  float4 v[4];
  float vmax = -3.0e38f;
#pragma unroll
  for (int i = 0; i < 4; i++) {
    v[i] = p[tid + i * 256];
    vmax = fmaxf(vmax, fmaxf(fmaxf(v[i].x, v[i].y), fmaxf(v[i].z, v[i].w)));
  }
#pragma unroll
  for (int off = 32; off > 0; off >>= 1)
    vmax = fmaxf(vmax, __shfl_xor(vmax, off, 64));

  __shared__ float red[4];
  const int wid = tid >> 6;
  if ((tid & 63) == 0) red[wid] = vmax;
  __syncthreads();
  vmax = fmaxf(fmaxf(red[0], red[1]), fmaxf(red[2], red[3]));
  __syncthreads();

  float s = 0.f;
#pragma unroll
  for (int i = 0; i < 4; i++) {
    v[i].x = expf(v[i].x - vmax);
    v[i].y = expf(v[i].y - vmax);
    v[i].z = expf(v[i].z - vmax);
    v[i].w = expf(v[i].w - vmax);
    s += (v[i].x + v[i].y) + (v[i].z + v[i].w);
  }
#pragma unroll
  for (int off = 32; off > 0; off >>= 1) s += __shfl_xor(s, off, 64);
  if ((tid & 63) == 0) red[wid] = s;
  __syncthreads();
  s = (red[0] + red[1]) + (red[2] + red[3]);

  const float inv = 1.0f / s;
#pragma unroll
  for (int i = 0; i < 4; i++) {
    bf16x4 o;
    o[0] = (__bf16)(v[i].x * inv);
    o[1] = (__bf16)(v[i].y * inv);
    o[2] = (__bf16)(v[i].z * inv);
    o[3] = (__bf16)(v[i].w * inv);
    q[tid + i * 256] = o;
  }
}

// ---------------------------------------------------------------------------
// x (fp32 [C,HW] per batch) -> xb (bf16 same layout) + xT (bf16 [HW,C]).
// 64x64 tiles via LDS. grid: (HW/64, C/64, B), block 256.
// ---------------------------------------------------------------------------
__global__ __launch_bounds__(256) void convert_x(
    const float* __restrict__ x, __bf16* __restrict__ xb,
    __bf16* __restrict__ xT) {
  __shared__ __bf16 t[64][66];  // 66: 132B pitch -> conflict-free columns
  const int j0 = blockIdx.x * 64;
  const int c0 = blockIdx.y * 64;
  const long bofs = (long)blockIdx.z * CC * HWN;
  const int j = threadIdx.x & 63;
  const int g = threadIdx.x >> 6;

#pragma unroll
  for (int r = 0; r < 16; r++) {
    const int i = r * 4 + g;
    const float v = x[bofs + (long)(c0 + i) * HWN + j0 + j];
    const __bf16 bv = (__bf16)v;
    xb[bofs + (long)(c0 + i) * HWN + j0 + j] = bv;
    t[j][i] = bv;
  }
  __syncthreads();
#pragma unroll
  for (int r = 0; r < 16; r++) {
    const int jj = r * 4 + g;
    xT[bofs + (long)(j0 + jj) * CC + c0 + j] = t[jj][j];
  }
}

// ---------------------------------------------------------------------------
// bf16 transpose: in [C,HW] per batch -> out [HW,C]. Same tiling.
// ---------------------------------------------------------------------------
__global__ __launch_bounds__(256) void transpose_bf16(
    const __bf16* __restrict__ in, __bf16* __restrict__ out) {
  __shared__ __bf16 t[64][66];
  const int j0 = blockIdx.x * 64;
  const int c0 = blockIdx.y * 64;
  const long bofs = (long)blockIdx.z * CC * HWN;
  const int j = threadIdx.x & 63;
  const int g = threadIdx.x >> 6;

#pragma unroll
  for (int r = 0; r < 16; r++) {
    const int i = r * 4 + g;
    t[j][i] = in[bofs + (long)(c0 + i) * HWN + j0 + j];
  }
  __syncthreads();
#pragma unroll
  for (int r = 0; r < 16; r++) {
    const int jj = r * 4 + g;
    out[bofs + (long)(j0 + jj) * CC + c0 + j] = t[jj][j];
  }
}

// ---------------------------------------------------------------------------
// Plan:
//  0. convert_x: x -> xb [C,HW] bf16, xT [HW,C] bf16
//  1. logitsB = wB·x + bB        (A=wB, B=xT)           -> d_out (fp32)
//  2. softmax rows -> Bm bf16                            -> ws.bm
//  3. M = Bm·x^T                 (A=Bm, B=xb, K=4096)    -> ws.Mb (bf16)
//  4. gdT = (wA·M^T + bA)/HW     (A=wA, B=Mb)            -> ws.gdT (bf16)
//  5. logitsV = wV·x + bV        (A=wV, B=xT)            -> d_out (fp32)
//  6. softmax rows -> av bf16                            -> ws.bm (reuse)
//  7. transpose av -> avT [HW,C]                         -> ws.xT (reuse)
//  8. out = gdT·av               (A=gdT, B=avT)          -> d_out (fp32)
// ws: 3 x 32MiB + 2 x 4MiB = 104 MiB.
// ---------------------------------------------------------------------------
extern "C" void kernel_launch(void* const* d_in, const int* in_sizes, int n_in,
                              void* d_out, int out_size, void* d_ws,
                              size_t ws_size, hipStream_t stream) {
  const float* x  = (const float*)d_in[0];
  const float* wA = (const float*)d_in[1];
  const float* bA = (const float*)d_in[2];
  const float* wB = (const float*)d_in[3];
  const float* bB = (const float*)d_in[4];
  const float* wV = (const float*)d_in[5];
  const float* bV = (const float*)d_in[6];
  float* out = (float*)d_out;

  const size_t nBCHW = (size_t)BB * CC * HWN;
  const size_t nBCC  = (size_t)BB * CC * CC;
  __bf16* xb  = (__bf16*)d_ws;          // [B,C,HW]
  __bf16* xT  = xb + nBCHW;             // [B,HW,C]; reused as avT after step 5
  __bf16* bm  = xT + nBCHW;             // [B,C,HW]; Bm then av
  __bf16* Mb  = bm + nBCHW;             // [B,C,C]
  __bf16* gdT = Mb + nBCC;              // [B,C,C]

  // First convert weights? No: weights are fp32 inputs — convert on the fly
  // is not supported by the GEMM; convert them via convert-lite below.
  // wA/wB/wV are [512,512] fp32 -> need bf16 row-major (k contiguous).
  // Reuse transpose-free conversion: treat as 512x512 grid with convert_x's
  // xb path only. Simplest: small dedicated lambda-like kernel launch using
  // convert_x would also write a transpose we don't need; do a plain cast
  // kernel instead (cheap: 3 MiB).
  __bf16* wAb = gdT + nBCC;             // [512,512]
  __bf16* wBb = wAb + (size_t)CC * CC;
  __bf16* wVb = wBb + (size_t)CC * CC;

  // plain fp32->bf16 cast kernels for the three weight matrices
  {
    struct Cast {
      static __global__ void run(const float* __restrict__ in,
                                 __bf16* __restrict__ o, int n) {
        int i = blockIdx.x * 256 + threadIdx.x;
        if (i < n) o[i] = (__bf16)in[i];
      }
    };
    const int n = CC * CC;
    hipLaunchKernelGGL(Cast::run, dim3((n + 255) / 256), dim3(256), 0, stream,
                       wA, wAb, n);
    hipLaunchKernelGGL(Cast::run, dim3((n + 255) / 256), dim3(256), 0, stream,
                       wB, wBb, n);
    hipLaunchKernelGGL(Cast::run, dim3((n + 255) / 256), dim3(256), 0, stream,
                       wV, wVb, n);
  }

  convert_x<<<dim3(HWN / 64, CC / 64, BB), 256, 0, stream>>>(x, xb, xT);

  const long sBC_HW = (long)CC * HWN;
  const long sCC = (long)CC * CC;

  // 1. logitsB -> d_out
  gemm_mfma_bt<1, float><<<dim3(HWN / 128, CC / 128, BB), 256, 0, stream>>>(
      wBb, xT, bB, out, CC, HWN, CC, 0, sBC_HW, sBC_HW, 1.0f);
  // 2. softmax -> bm
  softmax_rows_bf16<<<dim3(BB * CC), 256, 0, stream>>>(out, bm);
  // 3. M = Bm @ x^T -> Mb (bf16)
  gemm_mfma_bt<0, __bf16><<<dim3(CC / 128, CC / 128, BB), 256, 0, stream>>>(
      bm, xb, nullptr, Mb, CC, CC, HWN, sBC_HW, sBC_HW, sCC, 1.0f);
  // 4. gdT = (wA @ M^T + bA)/HW -> gdT (bf16)
  gemm_mfma_bt<1, __bf16><<<dim3(CC / 128, CC / 128, BB), 256, 0, stream>>>(
      wAb, Mb, bA, gdT, CC, CC, CC, 0, sCC, sCC, 1.0f / (float)HWN);
  // 5. logitsV -> d_out
  gemm_mfma_bt<1, float><<<dim3(HWN / 128, CC / 128, BB), 256, 0, stream>>>(
      wVb, xT, bV, out, CC, HWN, CC, 0, sBC_HW, sBC_HW, 1.0f);
  // 6. softmax -> av (bm buffer)
  softmax_rows_bf16<<<dim3(BB * CC), 256, 0, stream>>>(out, bm);
  // 7. avT -> xT buffer
  transpose_bf16<<<dim3(HWN / 64, CC / 64, BB), 256, 0, stream>>>(bm, xT);
  // 8. out = gdT @ av
  gemm_mfma_bt<0, float><<<dim3(HWN / 128, CC / 128, BB), 256, 0, stream>>>(
      gdT, xT, nullptr, out, CC, HWN, CC, sCC, sBC_HW, sBC_HW, 1.0f);
}

// Round 3
// 328.896 us; speedup vs baseline: 4.8423x; 1.1648x over previous
//
#include <hip/hip_runtime.h>
#include <math.h>

#define BB 8
#define CC 512
#define HWN 4096

typedef __bf16 bf16x8 __attribute__((ext_vector_type(8)));
typedef __bf16 bf16x4 __attribute__((ext_vector_type(4)));
typedef float f32x4 __attribute__((ext_vector_type(4)));

#define GLOBAL_AS __attribute__((address_space(1)))
#define LDS_AS __attribute__((address_space(3)))

static __device__ __forceinline__ void async_copy16(const void* g, void* l) {
  __builtin_amdgcn_global_load_lds((const GLOBAL_AS unsigned int*)g,
                                   (LDS_AS unsigned int*)l, 16, 0, 0);
}

// ---------------------------------------------------------------------------
// MFMA bf16 GEMM, BT form: C[m,n] = alpha*(sum_k A[m,k]*B[n,k] + bias[m]?)
// A:[M,K] bf16 k-contig. B:[N,K] bf16 k-contig. C:[M,N] row-major OUT_T.
// 128x128 tile, BK=32, 256 thr = 4 waves (2x2), 4x4 16x16x32 MFMAs per wave.
// Staging: global_load_lds width=16 into UNPADDED As[128][32] (lane-order
// contiguous as the instruction requires; b128 frag reads are ~2-way = free).
// Split-K: grid.z = batch*ksl + slice; slice output at Cg + slice*sSlice.
// ---------------------------------------------------------------------------
template <int BIASMODE, typename OUT_T>
__global__ __launch_bounds__(256) void gemm_mfma_bt(
    const __bf16* __restrict__ Ag, const __bf16* __restrict__ Bg,
    const float* __restrict__ bias, OUT_T* __restrict__ Cg,
    int M, int N, int K, long sA, long sB, long sC, float alpha,
    int ksl, long sSlice) {
  __shared__ __bf16 As[128][32];
  __shared__ __bf16 Bs[128][32];

  const int tid = threadIdx.x;
  const int n0 = blockIdx.x * 128;
  const int m0 = blockIdx.y * 128;
  const int bz = blockIdx.z;
  const int batch = bz / ksl;
  const int slice = bz - batch * ksl;
  const int kLen = K / ksl;
  const int kBeg = slice * kLen, kEnd = kBeg + kLen;
  Ag += (long)batch * sA;
  Bg += (long)batch * sB;
  Cg += (long)batch * sC + (long)slice * sSlice;

  const int lane = tid & 63;
  const int w = tid >> 6;         // wave id 0..3
  const int wr = w >> 1;          // wave row (m)
  const int wc = w & 1;           // wave col (n)
  const int l15 = lane & 15;
  const int quad = lane >> 4;

  // staging addressing: instruction i covers LDS bytes [i*4096 + w*1024 +
  // lane*16): row = i*64 + w*16 + (lane>>2), 16B seg = lane&3.
  const int srow = w * 16 + (lane >> 2);
  const int scol = (lane & 3) * 8;

  f32x4 acc[4][4] = {};

  for (int k0 = kBeg; k0 < kEnd; k0 += 32) {
    __syncthreads();
#pragma unroll
    for (int i = 0; i < 2; i++) {
      async_copy16(&Ag[(long)(m0 + i * 64 + srow) * K + k0 + scol],
                   (char*)&As[0][0] + i * 4096 + w * 1024);
      async_copy16(&Bg[(long)(n0 + i * 64 + srow) * K + k0 + scol],
                   (char*)&Bs[0][0] + i * 4096 + w * 1024);
    }
    __syncthreads();

    bf16x8 af[4], bfr[4];
#pragma unroll
    for (int t = 0; t < 4; t++) {
      af[t]  = *(const bf16x8*)&As[wr * 64 + t * 16 + l15][quad * 8];
      bfr[t] = *(const bf16x8*)&Bs[wc * 64 + t * 16 + l15][quad * 8];
    }
#pragma unroll
    for (int ti = 0; ti < 4; ti++)
#pragma unroll
      for (int tj = 0; tj < 4; tj++)
        acc[ti][tj] = __builtin_amdgcn_mfma_f32_16x16x32_bf16(
            af[ti], bfr[tj], acc[ti][tj], 0, 0, 0);
  }

#pragma unroll
  for (int ti = 0; ti < 4; ti++) {
#pragma unroll
    for (int tj = 0; tj < 4; tj++) {
#pragma unroll
      for (int r = 0; r < 4; r++) {
        const int m = m0 + wr * 64 + ti * 16 + quad * 4 + r;
        const int n = n0 + wc * 64 + tj * 16 + l15;
        float v = acc[ti][tj][r];
        if (BIASMODE == 1) v += bias[m];
        Cg[(long)m * N + n] = (OUT_T)(v * alpha);
      }
    }
  }
}

// ---------------------------------------------------------------------------
// Reduce split-K fp32 partials (ksl=4, slice stride sSl) -> bf16.
// ---------------------------------------------------------------------------
__global__ __launch_bounds__(256) void reduce_partials(
    const float* __restrict__ P, __bf16* __restrict__ out, int n, long sSl) {
  const int i = (blockIdx.x * 256 + threadIdx.x) * 4;
  if (i >= n) return;
  float4 a = *(const float4*)&P[i];
  float4 b = *(const float4*)&P[i + sSl];
  float4 c = *(const float4*)&P[i + 2 * sSl];
  float4 d = *(const float4*)&P[i + 3 * sSl];
  bf16x4 o;
  o[0] = (__bf16)(a.x + b.x + c.x + d.x);
  o[1] = (__bf16)(a.y + b.y + c.y + d.y);
  o[2] = (__bf16)(a.z + b.z + c.z + d.z);
  o[3] = (__bf16)(a.w + b.w + c.w + d.w);
  *(bf16x4*)&out[i] = o;
}

// ---------------------------------------------------------------------------
// Row softmax over length-4096 rows: fp32 in -> bf16 out with row stride
// ldOut (elements). ldOut=8192 + out==(bf16*)in gives the in-place variant
// (each block fully loads its row into registers before writing -> safe).
// ---------------------------------------------------------------------------
__global__ __launch_bounds__(256) void softmax_rows_bf16(
    const float* __restrict__ in, __bf16* __restrict__ out, int ldOut) {
  const long row = blockIdx.x;
  const float4* p = reinterpret_cast<const float4*>(in + row * (long)HWN);
  bf16x4* q = reinterpret_cast<bf16x4*>(out + row * (long)ldOut);
  const int tid = threadIdx.x;

  float4 v[4];
  float vmax = -3.0e38f;
#pragma unroll
  for (int i = 0; i < 4; i++) {
    v[i] = p[tid + i * 256];
    vmax = fmaxf(vmax, fmaxf(fmaxf(v[i].x, v[i].y), fmaxf(v[i].z, v[i].w)));
  }
#pragma unroll
  for (int off = 32; off > 0; off >>= 1)
    vmax = fmaxf(vmax, __shfl_xor(vmax, off, 64));

  __shared__ float red[4];
  const int wid = tid >> 6;
  if ((tid & 63) == 0) red[wid] = vmax;
  __syncthreads();
  vmax = fmaxf(fmaxf(red[0], red[1]), fmaxf(red[2], red[3]));
  __syncthreads();

  float s = 0.f;
#pragma unroll
  for (int i = 0; i < 4; i++) {
    v[i].x = expf(v[i].x - vmax);
    v[i].y = expf(v[i].y - vmax);
    v[i].z = expf(v[i].z - vmax);
    v[i].w = expf(v[i].w - vmax);
    s += (v[i].x + v[i].y) + (v[i].z + v[i].w);
  }
#pragma unroll
  for (int off = 32; off > 0; off >>= 1) s += __shfl_xor(s, off, 64);
  if ((tid & 63) == 0) red[wid] = s;
  __syncthreads();
  s = (red[0] + red[1]) + (red[2] + red[3]);

  const float inv = 1.0f / s;
#pragma unroll
  for (int i = 0; i < 4; i++) {
    bf16x4 o;
    o[0] = (__bf16)(v[i].x * inv);
    o[1] = (__bf16)(v[i].y * inv);
    o[2] = (__bf16)(v[i].z * inv);
    o[3] = (__bf16)(v[i].w * inv);
    q[tid + i * 256] = o;
  }
}

// x (fp32 [C,HW] per batch) -> xb (bf16 same layout) + xT (bf16 [HW,C]).
__global__ __launch_bounds__(256) void convert_x(
    const float* __restrict__ x, __bf16* __restrict__ xb,
    __bf16* __restrict__ xT) {
  __shared__ __bf16 t[64][66];
  const int j0 = blockIdx.x * 64;
  const int c0 = blockIdx.y * 64;
  const long bofs = (long)blockIdx.z * CC * HWN;
  const int j = threadIdx.x & 63;
  const int g = threadIdx.x >> 6;

#pragma unroll
  for (int r = 0; r < 16; r++) {
    const int i = r * 4 + g;
    const float v = x[bofs + (long)(c0 + i) * HWN + j0 + j];
    const __bf16 bv = (__bf16)v;
    xb[bofs + (long)(c0 + i) * HWN + j0 + j] = bv;
    t[j][i] = bv;
  }
  __syncthreads();
#pragma unroll
  for (int r = 0; r < 16; r++) {
    const int jj = r * 4 + g;
    xT[bofs + (long)(j0 + jj) * CC + c0 + j] = t[jj][j];
  }
}

// bf16 transpose with input row stride ldIn and batch strides sIn/sOut:
// out[b][j][c] = in[b*sIn + c*ldIn + j]; out batch b at sOut, [HW,C].
__global__ __launch_bounds__(256) void transpose_bf16_s(
    const __bf16* __restrict__ in, __bf16* __restrict__ out, int ldIn,
    long sIn, long sOut) {
  __shared__ __bf16 t[64][66];
  const int j0 = blockIdx.x * 64;
  const int c0 = blockIdx.y * 64;
  const int j = threadIdx.x & 63;
  const int g = threadIdx.x >> 6;

#pragma unroll
  for (int r = 0; r < 16; r++) {
    const int i = r * 4 + g;
    t[j][i] = in[(long)blockIdx.z * sIn + (long)(c0 + i) * ldIn + j0 + j];
  }
  __syncthreads();
#pragma unroll
  for (int r = 0; r < 16; r++) {
    const int jj = r * 4 + g;
    out[(long)blockIdx.z * sOut + (long)(j0 + jj) * CC + c0 + j] = t[jj][j];
  }
}

// cast three 512x512 fp32 weight matrices to bf16 in one dispatch
__global__ __launch_bounds__(256) void cast_weights(
    const float* __restrict__ a, const float* __restrict__ b,
    const float* __restrict__ c, __bf16* __restrict__ oa,
    __bf16* __restrict__ ob, __bf16* __restrict__ oc) {
  const int which = blockIdx.x >> 8;               // 256 blocks per matrix
  const int i = ((blockIdx.x & 255) * 256 + threadIdx.x) * 4;  // <262144
  const float* in = which == 0 ? a : (which == 1 ? b : c);
  __bf16* out = which == 0 ? oa : (which == 1 ? ob : oc);
  float4 v = *(const float4*)&in[i];
  bf16x4 o;
  o[0] = (__bf16)v.x; o[1] = (__bf16)v.y; o[2] = (__bf16)v.z; o[3] = (__bf16)v.w;
  *(bf16x4*)&out[i] = o;
}

// ---------------------------------------------------------------------------
// Order (d_out reuse: B-logits -> V-logits -> av(bf16, in-place, stride 8192)
// -> split-K partials -> final out):
//  0. cast_weights; convert_x -> xb [C,HW], xT [HW,C]
//  1. B-logits = wB·x + bB   (A=wBb,B=xT)          -> d_out fp32
//  2. softmax -> bm bf16 (ws)
//  5. V-logits = wV·x + bV   (A=wVb,B=xT)          -> d_out fp32
//  6. softmax in-place       -> av bf16 inside d_out, row stride 8192
//  7. transpose av -> avT into xT region (xT dead)
//  3. M partials: split-K=4  (A=bm,B=xb)           -> d_out fp32 [4][B,C,C]
//  3b reduce partials -> Mb bf16 (ws)
//  4. gdT = (wA·M^T + bA)/HW (A=wAb,B=Mb)          -> gdT bf16 (ws)
//  8. out = gdT·avT          (A=gdT,B=xT)          -> d_out fp32
// ws: 3x32 MiB + 4 + 4 + 1.5 = ~105.5 MiB (unchanged from round 2).
// ---------------------------------------------------------------------------
extern "C" void kernel_launch(void* const* d_in, const int* in_sizes, int n_in,
                              void* d_out, int out_size, void* d_ws,
                              size_t ws_size, hipStream_t stream) {
  const float* x  = (const float*)d_in[0];
  const float* wA = (const float*)d_in[1];
  const float* bA = (const float*)d_in[2];
  const float* wB = (const float*)d_in[3];
  const float* bB = (const float*)d_in[4];
  const float* wV = (const float*)d_in[5];
  const float* bV = (const float*)d_in[6];
  float* out = (float*)d_out;

  const size_t nBCHW = (size_t)BB * CC * HWN;
  const size_t nBCC  = (size_t)BB * CC * CC;
  __bf16* xb  = (__bf16*)d_ws;          // [B,C,HW]; x bf16
  __bf16* xT  = xb + nBCHW;             // [B,HW,C]; x^T, later avT
  __bf16* bm  = xT + nBCHW;             // [B,C,HW]; Bm
  __bf16* Mb  = bm + nBCHW;             // [B,C,C]
  __bf16* gdT = Mb + nBCC;              // [B,C,C]
  __bf16* wAb = gdT + nBCC;
  __bf16* wBb = wAb + (size_t)CC * CC;
  __bf16* wVb = wBb + (size_t)CC * CC;

  const long sBC_HW = (long)CC * HWN;
  const long sCC = (long)CC * CC;

  cast_weights<<<dim3(768), 256, 0, stream>>>(wA, wB, wV, wAb, wBb, wVb);
  convert_x<<<dim3(HWN / 64, CC / 64, BB), 256, 0, stream>>>(x, xb, xT);

  // 1. B-logits -> d_out
  gemm_mfma_bt<1, float><<<dim3(HWN / 128, CC / 128, BB), 256, 0, stream>>>(
      wBb, xT, bB, out, CC, HWN, CC, 0, sBC_HW, sBC_HW, 1.0f, 1, 0);
  // 2. softmax -> bm
  softmax_rows_bf16<<<dim3(BB * CC), 256, 0, stream>>>(out, bm, HWN);
  // 5. V-logits -> d_out
  gemm_mfma_bt<1, float><<<dim3(HWN / 128, CC / 128, BB), 256, 0, stream>>>(
      wVb, xT, bV, out, CC, HWN, CC, 0, sBC_HW, sBC_HW, 1.0f, 1, 0);
  // 6. softmax in place: av bf16 rows at stride 8192 inside d_out
  softmax_rows_bf16<<<dim3(BB * CC), 256, 0, stream>>>(
      out, (__bf16*)out, 2 * HWN);
  // 7. avT -> xT region
  transpose_bf16_s<<<dim3(HWN / 64, CC / 64, BB), 256, 0, stream>>>(
      (const __bf16*)out, xT, 2 * HWN, (long)CC * 2 * HWN, (long)HWN * CC);
  // 3. M split-K=4 partials -> d_out (fp32, slice stride nBCC)
  gemm_mfma_bt<0, float><<<dim3(CC / 128, CC / 128, BB * 4), 256, 0, stream>>>(
      bm, xb, nullptr, out, CC, CC, HWN, sBC_HW, sBC_HW, sCC, 1.0f, 4,
      (long)nBCC);
  // 3b. reduce -> Mb
  reduce_partials<<<dim3(nBCC / 1024), 256, 0, stream>>>(out, Mb, (int)nBCC,
                                                         (long)nBCC);
  // 4. gdT = (wA @ M^T + bA)/HW
  gemm_mfma_bt<1, __bf16><<<dim3(CC / 128, CC / 128, BB), 256, 0, stream>>>(
      wAb, Mb, bA, gdT, CC, CC, CC, 0, sCC, sCC, 1.0f / (float)HWN, 1, 0);
  // 8. out = gdT @ avT -> d_out
  gemm_mfma_bt<0, float><<<dim3(HWN / 128, CC / 128, BB), 256, 0, stream>>>(
      gdT, xT, nullptr, out, CC, HWN, CC, sCC, sBC_HW, sBC_HW, 1.0f, 1, 0);
}

// Round 4
// 320.461 us; speedup vs baseline: 4.9698x; 1.0263x over previous
//
#include <hip/hip_runtime.h>
#include <math.h>

#define BB 8
#define CC 512
#define HWN 4096

typedef __bf16 bf16x8 __attribute__((ext_vector_type(8)));
typedef __bf16 bf16x4 __attribute__((ext_vector_type(4)));
typedef float f32x4 __attribute__((ext_vector_type(4)));

#define GLOBAL_AS __attribute__((address_space(1)))
#define LDS_AS __attribute__((address_space(3)))

static __device__ __forceinline__ void async_copy16(const void* g, void* l) {
  __builtin_amdgcn_global_load_lds((const GLOBAL_AS unsigned int*)g,
                                   (LDS_AS unsigned int*)l, 16, 0, 0);
}

// ---------------------------------------------------------------------------
// MFMA bf16 GEMM, BT form: C[m,n] = alpha*(sum_k A[m,k]*B[n,k] + bias[m]?)
// A:[M,K] bf16 k-contig. B:[N,K] bf16 k-contig. C:[M,N] row-major OUT_T.
// 128x128 tile, BK=32, 256 thr = 4 waves (2x2), 4x4 16x16x32 MFMAs per wave.
// Staging: global_load_lds width=16, unpadded LDS (lane-order contiguous).
// Split-K: grid.z = batch*ksl + slice; slice output at Cg + slice*sSlice.
// ---------------------------------------------------------------------------
template <int BIASMODE, typename OUT_T>
__global__ __launch_bounds__(256) void gemm_mfma_bt(
    const __bf16* __restrict__ Ag, const __bf16* __restrict__ Bg,
    const float* __restrict__ bias, OUT_T* __restrict__ Cg,
    int M, int N, int K, long sA, long sB, long sC, float alpha,
    int ksl, long sSlice) {
  __shared__ __bf16 As[128][32];
  __shared__ __bf16 Bs[128][32];

  const int tid = threadIdx.x;
  const int n0 = blockIdx.x * 128;
  const int m0 = blockIdx.y * 128;
  const int bz = blockIdx.z;
  const int batch = bz / ksl;
  const int slice = bz - batch * ksl;
  const int kLen = K / ksl;
  const int kBeg = slice * kLen, kEnd = kBeg + kLen;
  Ag += (long)batch * sA;
  Bg += (long)batch * sB;
  Cg += (long)batch * sC + (long)slice * sSlice;

  const int lane = tid & 63;
  const int w = tid >> 6;
  const int wr = w >> 1;
  const int wc = w & 1;
  const int l15 = lane & 15;
  const int quad = lane >> 4;

  const int srow = w * 16 + (lane >> 2);
  const int scol = (lane & 3) * 8;

  f32x4 acc[4][4] = {};

  for (int k0 = kBeg; k0 < kEnd; k0 += 32) {
    __syncthreads();
#pragma unroll
    for (int i = 0; i < 2; i++) {
      async_copy16(&Ag[(long)(m0 + i * 64 + srow) * K + k0 + scol],
                   (char*)&As[0][0] + i * 4096 + w * 1024);
      async_copy16(&Bg[(long)(n0 + i * 64 + srow) * K + k0 + scol],
                   (char*)&Bs[0][0] + i * 4096 + w * 1024);
    }
    __syncthreads();

    bf16x8 af[4], bfr[4];
#pragma unroll
    for (int t = 0; t < 4; t++) {
      af[t]  = *(const bf16x8*)&As[wr * 64 + t * 16 + l15][quad * 8];
      bfr[t] = *(const bf16x8*)&Bs[wc * 64 + t * 16 + l15][quad * 8];
    }
#pragma unroll
    for (int ti = 0; ti < 4; ti++)
#pragma unroll
      for (int tj = 0; tj < 4; tj++)
        acc[ti][tj] = __builtin_amdgcn_mfma_f32_16x16x32_bf16(
            af[ti], bfr[tj], acc[ti][tj], 0, 0, 0);
  }

#pragma unroll
  for (int ti = 0; ti < 4; ti++) {
#pragma unroll
    for (int tj = 0; tj < 4; tj++) {
#pragma unroll
      for (int r = 0; r < 4; r++) {
        const int m = m0 + wr * 64 + ti * 16 + quad * 4 + r;
        const int n = n0 + wc * 64 + tj * 16 + l15;
        float v = acc[ti][tj][r];
        if (BIASMODE == 1) v += bias[m];
        Cg[(long)m * N + n] = (OUT_T)(v * alpha);
      }
    }
  }
}

// ---------------------------------------------------------------------------
// Dual softmax over bf16 logit rows [B,1024,HWN] in d_out.
// Row c<512 (B-logits): write normalized bf16 row to bm[b,c,:].
// Row c>=512 (V-logits): write back in place (av).
// ---------------------------------------------------------------------------
__global__ __launch_bounds__(256) void softmax_dual_bf16(
    __bf16* __restrict__ logits, __bf16* __restrict__ bm) {
  const int row = blockIdx.x;                 // 0..8191
  const int b = row >> 10, c = row & 1023;
  __bf16* src = logits + ((long)b * 1024 + c) * HWN;
  __bf16* dst = (c < 512) ? (bm + ((long)b * 512 + c) * HWN) : src;
  const int tid = threadIdx.x;

  const bf16x8* p = reinterpret_cast<const bf16x8*>(src);
  bf16x8* q = reinterpret_cast<bf16x8*>(dst);

  float v[16];
  float vmax = -3.0e38f;
#pragma unroll
  for (int i = 0; i < 2; i++) {
    bf16x8 t = p[tid + i * 256];
#pragma unroll
    for (int j = 0; j < 8; j++) {
      v[i * 8 + j] = (float)t[j];
      vmax = fmaxf(vmax, v[i * 8 + j]);
    }
  }
#pragma unroll
  for (int off = 32; off > 0; off >>= 1)
    vmax = fmaxf(vmax, __shfl_xor(vmax, off, 64));

  __shared__ float red[4];
  const int wid = tid >> 6;
  if ((tid & 63) == 0) red[wid] = vmax;
  __syncthreads();
  vmax = fmaxf(fmaxf(red[0], red[1]), fmaxf(red[2], red[3]));
  __syncthreads();

  float s = 0.f;
#pragma unroll
  for (int i = 0; i < 16; i++) {
    v[i] = expf(v[i] - vmax);
    s += v[i];
  }
#pragma unroll
  for (int off = 32; off > 0; off >>= 1) s += __shfl_xor(s, off, 64);
  if ((tid & 63) == 0) red[wid] = s;
  __syncthreads();
  s = (red[0] + red[1]) + (red[2] + red[3]);

  const float inv = 1.0f / s;
#pragma unroll
  for (int i = 0; i < 2; i++) {
    bf16x8 o;
#pragma unroll
    for (int j = 0; j < 8; j++) o[j] = (__bf16)(v[i * 8 + j] * inv);
    q[tid + i * 256] = o;
  }
}

// Reduce split-K fp32 partials (8 slices, stride sSl) -> bf16. Per-batch
// region of nPer floats at batch stride sBat.
__global__ __launch_bounds__(256) void reduce_partials8(
    const float* __restrict__ P, __bf16* __restrict__ out, long sBat,
    long sSl) {
  const int b = blockIdx.x >> 8;                       // 256 blocks/batch
  const int il = ((blockIdx.x & 255) * 256 + threadIdx.x) * 4;  // <262144
  const float* p = P + (long)b * sBat + il;
  float4 s0 = *(const float4*)&p[0];
#pragma unroll
  for (int sl = 1; sl < 8; sl++) {
    float4 t = *(const float4*)&p[sl * sSl];
    s0.x += t.x; s0.y += t.y; s0.z += t.z; s0.w += t.w;
  }
  bf16x4 o;
  o[0] = (__bf16)s0.x; o[1] = (__bf16)s0.y; o[2] = (__bf16)s0.z;
  o[3] = (__bf16)s0.w;
  *(bf16x4*)&out[(long)b * 262144 + il] = o;
}

// x (fp32 [C,HW] per batch) -> xb (bf16 same layout) + xT (bf16 [HW,C]).
__global__ __launch_bounds__(256) void convert_x(
    const float* __restrict__ x, __bf16* __restrict__ xb,
    __bf16* __restrict__ xT) {
  __shared__ __bf16 t[64][66];
  const int j0 = blockIdx.x * 64;
  const int c0 = blockIdx.y * 64;
  const long bofs = (long)blockIdx.z * CC * HWN;
  const int j = threadIdx.x & 63;
  const int g = threadIdx.x >> 6;

#pragma unroll
  for (int r = 0; r < 16; r++) {
    const int i = r * 4 + g;
    const float v = x[bofs + (long)(c0 + i) * HWN + j0 + j];
    const __bf16 bv = (__bf16)v;
    xb[bofs + (long)(c0 + i) * HWN + j0 + j] = bv;
    t[j][i] = bv;
  }
  __syncthreads();
#pragma unroll
  for (int r = 0; r < 16; r++) {
    const int jj = r * 4 + g;
    xT[bofs + (long)(j0 + jj) * CC + c0 + j] = t[jj][j];
  }
}

// bf16 transpose: out[b*sOut + j*CC + c] = in[b*sIn + c*ldIn + j]
__global__ __launch_bounds__(256) void transpose_bf16_s(
    const __bf16* __restrict__ in, __bf16* __restrict__ out, int ldIn,
    long sIn, long sOut) {
  __shared__ __bf16 t[64][66];
  const int j0 = blockIdx.x * 64;
  const int c0 = blockIdx.y * 64;
  const int j = threadIdx.x & 63;
  const int g = threadIdx.x >> 6;

#pragma unroll
  for (int r = 0; r < 16; r++) {
    const int i = r * 4 + g;
    t[j][i] = in[(long)blockIdx.z * sIn + (long)(c0 + i) * ldIn + j0 + j];
  }
  __syncthreads();
#pragma unroll
  for (int r = 0; r < 16; r++) {
    const int jj = r * 4 + g;
    out[(long)blockIdx.z * sOut + (long)(j0 + jj) * CC + c0 + j] = t[jj][j];
  }
}

// Cast weights: blocks 0-255 wB->wBVb[0:512], 256-511 wV->wBVb[512:1024],
// 512-767 wA->wAb, block 768 packs biases [bB;bV] fp32.
__global__ __launch_bounds__(256) void cast_weights(
    const float* __restrict__ wA, const float* __restrict__ wB,
    const float* __restrict__ wV, const float* __restrict__ bB,
    const float* __restrict__ bV, __bf16* __restrict__ wAb,
    __bf16* __restrict__ wBVb, float* __restrict__ bBV) {
  if (blockIdx.x == 768) {
#pragma unroll
    for (int j = 0; j < 4; j++) {
      const int i = threadIdx.x * 4 + j;
      bBV[i] = (i < 512) ? bB[i] : bV[i - 512];
    }
    return;
  }
  const int which = blockIdx.x >> 8;
  const int i = ((blockIdx.x & 255) * 256 + threadIdx.x) * 4;
  const float* in = which == 0 ? wB : (which == 1 ? wV : wA);
  __bf16* out = which == 0 ? wBVb
                           : (which == 1 ? wBVb + 262144 : wAb);
  float4 v = *(const float4*)&in[i];
  bf16x4 o;
  o[0] = (__bf16)v.x; o[1] = (__bf16)v.y; o[2] = (__bf16)v.z;
  o[3] = (__bf16)v.w;
  *(bf16x4*)&out[i] = o;
}

// ---------------------------------------------------------------------------
// Plan:
//  0. cast_weights (wBV stacked [1024,512] bf16, bBV [1024] f32); convert_x
//  1. logits = wBV·x + bBV  (A=wBVb,B=xT, M=1024)   -> d_out bf16 [B,1024,HW]
//  2. softmax_dual: B-rows -> bm (ws), V-rows -> in place (av)
//  3. transpose av -> avT into xT region (xT dead after step 1)
//  4. M partials split-K=8 (A=bm,B=xb)              -> d_out fp32 (all dead)
//  5. reduce -> Mb bf16
//  6. gdT = (wA·M^T + bA)/HW (A=wAb,B=Mb)           -> gdT bf16
//  7. out = gdT·avT          (A=gdT,B=xT)           -> d_out fp32
// ws: 32+32+32+4+4+1+0.5+~0 = 105.5 MiB.
// ---------------------------------------------------------------------------
extern "C" void kernel_launch(void* const* d_in, const int* in_sizes, int n_in,
                              void* d_out, int out_size, void* d_ws,
                              size_t ws_size, hipStream_t stream) {
  const float* x  = (const float*)d_in[0];
  const float* wA = (const float*)d_in[1];
  const float* bA = (const float*)d_in[2];
  const float* wB = (const float*)d_in[3];
  const float* bB = (const float*)d_in[4];
  const float* wV = (const float*)d_in[5];
  const float* bV = (const float*)d_in[6];
  float* out = (float*)d_out;

  const size_t nBCHW = (size_t)BB * CC * HWN;   // 16M
  const size_t nBCC  = (size_t)BB * CC * CC;    // 2M
  __bf16* xb   = (__bf16*)d_ws;          // [B,C,HW]
  __bf16* xT   = xb + nBCHW;             // [B,HW,C]; later avT
  __bf16* bm   = xT + nBCHW;             // [B,C,HW]
  __bf16* Mb   = bm + nBCHW;             // [B,C,C]
  __bf16* gdT  = Mb + nBCC;              // [B,C,C]
  __bf16* wBVb = gdT + nBCC;             // [1024,512]
  __bf16* wAb  = wBVb + (size_t)1024 * CC;
  float*  bBV  = (float*)(wAb + (size_t)CC * CC);  // [1024]

  const long sBC_HW = (long)CC * HWN;    // 2097152
  const long sCC = (long)CC * CC;        // 262144

  cast_weights<<<dim3(769), 256, 0, stream>>>(wA, wB, wV, bB, bV, wAb, wBVb,
                                              bBV);
  convert_x<<<dim3(HWN / 64, CC / 64, BB), 256, 0, stream>>>(x, xb, xT);

  __bf16* logits = (__bf16*)d_out;       // [B,1024,HW] bf16 == 64 MiB

  // 1. merged logits GEMM (M=1024): rows 0-511 B-logits, 512-1023 V-logits
  gemm_mfma_bt<1, __bf16><<<dim3(HWN / 128, 1024 / 128, BB), 256, 0, stream>>>(
      wBVb, xT, bBV, logits, 1024, HWN, CC, 0, sBC_HW, (long)1024 * HWN, 1.0f,
      1, 0);
  // 2. dual softmax
  softmax_dual_bf16<<<dim3(BB * 1024), 256, 0, stream>>>(logits, bm);
  // 3. avT (av rows live at logits + b*4194304 + 2097152 + c*4096)
  transpose_bf16_s<<<dim3(HWN / 64, CC / 64, BB), 256, 0, stream>>>(
      logits + 2097152, xT, HWN, (long)1024 * HWN, (long)HWN * CC);
  // 4. M split-K=8 partials -> d_out fp32: batch region 2M floats, slice 256K
  gemm_mfma_bt<0, float><<<dim3(CC / 128, CC / 128, BB * 8), 256, 0, stream>>>(
      bm, xb, nullptr, out, CC, CC, HWN, sBC_HW, sBC_HW, (long)2097152, 1.0f,
      8, (long)262144);
  // 5. reduce -> Mb
  reduce_partials8<<<dim3(BB * 256), 256, 0, stream>>>(out, Mb, 2097152,
                                                       262144);
  // 6. gdT = (wA @ M^T + bA)/HW
  gemm_mfma_bt<1, __bf16><<<dim3(CC / 128, CC / 128, BB), 256, 0, stream>>>(
      wAb, Mb, bA, gdT, CC, CC, CC, 0, sCC, sCC, 1.0f / (float)HWN, 1, 0);
  // 7. out = gdT @ avT -> d_out
  gemm_mfma_bt<0, float><<<dim3(HWN / 128, CC / 128, BB), 256, 0, stream>>>(
      gdT, xT, nullptr, out, CC, HWN, CC, sCC, sBC_HW, sBC_HW, 1.0f, 1, 0);
}

// Round 5
// 295.499 us; speedup vs baseline: 5.3896x; 1.0845x over previous
//
#include <hip/hip_runtime.h>
#include <math.h>

#define BB 8
#define CC 512
#define HWN 4096

typedef __bf16 bf16x8 __attribute__((ext_vector_type(8)));
typedef __bf16 bf16x4 __attribute__((ext_vector_type(4)));
typedef float f32x4 __attribute__((ext_vector_type(4)));

#define GLOBAL_AS __attribute__((address_space(1)))
#define LDS_AS __attribute__((address_space(3)))

static __device__ __forceinline__ void async_copy16(const void* g, void* l) {
  __builtin_amdgcn_global_load_lds((const GLOBAL_AS unsigned int*)g,
                                   (LDS_AS unsigned int*)l, 16, 0, 0);
}

// ---------------------------------------------------------------------------
// MFMA bf16 GEMM, BT form: C[m,n] = alpha*(sum_k A[m,k]*B[n,k] + bias[m]?)
// A:[M,K] bf16 k-contig. B:[N,K] bf16 k-contig. C:[M,N] row-major OUT_T.
// 128x128 tile, BK=64 as TWO 32-k half-buffers (keeps 64B-pitch LDS rows ->
// conflict-free b128 frag reads AND valid wave-uniform global_load_lds dst).
// Halves barrier count vs BK=32 — the drain before s_barrier was the limiter
// at K=512 (16 iters). 256 thr = 4 waves (2x2), 4x4 16x16x32 MFMAs per wave.
// Split-K: grid.z = batch*ksl + slice; slice output at Cg + slice*sSlice.
// ---------------------------------------------------------------------------
template <int BIASMODE, typename OUT_T>
__global__ __launch_bounds__(256) void gemm_mfma_bt(
    const __bf16* __restrict__ Ag, const __bf16* __restrict__ Bg,
    const float* __restrict__ bias, OUT_T* __restrict__ Cg,
    int M, int N, int K, long sA, long sB, long sC, float alpha,
    int ksl, long sSlice) {
  __shared__ __bf16 As[2][128][32];
  __shared__ __bf16 Bs[2][128][32];

  const int tid = threadIdx.x;
  const int n0 = blockIdx.x * 128;
  const int m0 = blockIdx.y * 128;
  const int bz = blockIdx.z;
  const int batch = bz / ksl;
  const int slice = bz - batch * ksl;
  const int kLen = K / ksl;
  const int kBeg = slice * kLen, kEnd = kBeg + kLen;
  Ag += (long)batch * sA;
  Bg += (long)batch * sB;
  Cg += (long)batch * sC + (long)slice * sSlice;

  const int lane = tid & 63;
  const int w = tid >> 6;
  const int wr = w >> 1, wc = w & 1;
  const int l15 = lane & 15, quad = lane >> 4;

  // Staging map (per half h, sub-chunk j): wave w covers LDS bytes
  // [w*2048 + j*1024, +1024) of As[h]; row = w*32 + j*16 + (lane>>2),
  // 16B seg = lane&3. Global k-offset = k0 + h*32 + (lane&3)*8.
  const int srow = w * 32 + (lane >> 2);
  const int scol = (lane & 3) * 8;

  f32x4 acc[4][4] = {};

  for (int k0 = kBeg; k0 < kEnd; k0 += 64) {
    __syncthreads();
#pragma unroll
    for (int h = 0; h < 2; h++) {
#pragma unroll
      for (int j = 0; j < 2; j++) {
        async_copy16(&Ag[(long)(m0 + srow + j * 16) * K + k0 + h * 32 + scol],
                     (char*)&As[h][0][0] + w * 2048 + j * 1024);
        async_copy16(&Bg[(long)(n0 + srow + j * 16) * K + k0 + h * 32 + scol],
                     (char*)&Bs[h][0][0] + w * 2048 + j * 1024);
      }
    }
    __syncthreads();

#pragma unroll
    for (int h = 0; h < 2; h++) {
      bf16x8 af[4], bfr[4];
#pragma unroll
      for (int t = 0; t < 4; t++) {
        af[t]  = *(const bf16x8*)&As[h][wr * 64 + t * 16 + l15][quad * 8];
        bfr[t] = *(const bf16x8*)&Bs[h][wc * 64 + t * 16 + l15][quad * 8];
      }
#pragma unroll
      for (int ti = 0; ti < 4; ti++)
#pragma unroll
        for (int tj = 0; tj < 4; tj++)
          acc[ti][tj] = __builtin_amdgcn_mfma_f32_16x16x32_bf16(
              af[ti], bfr[tj], acc[ti][tj], 0, 0, 0);
    }
  }

#pragma unroll
  for (int ti = 0; ti < 4; ti++) {
#pragma unroll
    for (int tj = 0; tj < 4; tj++) {
#pragma unroll
      for (int r = 0; r < 4; r++) {
        const int m = m0 + wr * 64 + ti * 16 + quad * 4 + r;
        const int n = n0 + wc * 64 + tj * 16 + l15;
        float v = acc[ti][tj][r];
        if (BIASMODE == 1) v += bias[m];
        Cg[(long)m * N + n] = (OUT_T)(v * alpha);
      }
    }
  }
}

// ---------------------------------------------------------------------------
// Dual softmax over bf16 logit rows [B,1024,HWN] in d_out.
// Row c<512 (B-logits): write normalized bf16 row to bm[b,c,:].
// Row c>=512 (V-logits): write back in place (av).
// ---------------------------------------------------------------------------
__global__ __launch_bounds__(256) void softmax_dual_bf16(
    __bf16* __restrict__ logits, __bf16* __restrict__ bm) {
  const int row = blockIdx.x;                 // 0..8191
  const int b = row >> 10, c = row & 1023;
  __bf16* src = logits + ((long)b * 1024 + c) * HWN;
  __bf16* dst = (c < 512) ? (bm + ((long)b * 512 + c) * HWN) : src;
  const int tid = threadIdx.x;

  const bf16x8* p = reinterpret_cast<const bf16x8*>(src);
  bf16x8* q = reinterpret_cast<bf16x8*>(dst);

  float v[16];
  float vmax = -3.0e38f;
#pragma unroll
  for (int i = 0; i < 2; i++) {
    bf16x8 t = p[tid + i * 256];
#pragma unroll
    for (int j = 0; j < 8; j++) {
      v[i * 8 + j] = (float)t[j];
      vmax = fmaxf(vmax, v[i * 8 + j]);
    }
  }
#pragma unroll
  for (int off = 32; off > 0; off >>= 1)
    vmax = fmaxf(vmax, __shfl_xor(vmax, off, 64));

  __shared__ float red[4];
  const int wid = tid >> 6;
  if ((tid & 63) == 0) red[wid] = vmax;
  __syncthreads();
  vmax = fmaxf(fmaxf(red[0], red[1]), fmaxf(red[2], red[3]));
  __syncthreads();

  float s = 0.f;
#pragma unroll
  for (int i = 0; i < 16; i++) {
    v[i] = expf(v[i] - vmax);
    s += v[i];
  }
#pragma unroll
  for (int off = 32; off > 0; off >>= 1) s += __shfl_xor(s, off, 64);
  if ((tid & 63) == 0) red[wid] = s;
  __syncthreads();
  s = (red[0] + red[1]) + (red[2] + red[3]);

  const float inv = 1.0f / s;
#pragma unroll
  for (int i = 0; i < 2; i++) {
    bf16x8 o;
#pragma unroll
    for (int j = 0; j < 8; j++) o[j] = (__bf16)(v[i * 8 + j] * inv);
    q[tid + i * 256] = o;
  }
}

// ---------------------------------------------------------------------------
// Reduce bf16 split-K partials (8 slices of 262144 elems per batch, batch
// stride 2097152) -> bf16 Mb. One thread = 8 output elems.
// ---------------------------------------------------------------------------
__global__ __launch_bounds__(256) void reduce_partials8b(
    const __bf16* __restrict__ P, __bf16* __restrict__ out) {
  const long i = ((long)blockIdx.x * 256 + threadIdx.x) * 8;  // < 2M
  const int b = (int)(i >> 18);
  const long il = i & 262143;
  const __bf16* p = P + (long)b * 2097152 + il;
  float s[8] = {};
#pragma unroll
  for (int sl = 0; sl < 8; sl++) {
    bf16x8 t = *(const bf16x8*)&p[(long)sl * 262144];
#pragma unroll
    for (int j = 0; j < 8; j++) s[j] += (float)t[j];
  }
  bf16x8 o;
#pragma unroll
  for (int j = 0; j < 8; j++) o[j] = (__bf16)s[j];
  *(bf16x8*)&out[i] = o;
}

// ---------------------------------------------------------------------------
// z<8:  x (fp32 [C,HW] batch z) -> xb (bf16 same layout) + xT (bf16 [HW,C]).
// z==8: weight/bias conversion (wB,wV -> wBVb stacked; wA -> wAb; bBV pack).
// ---------------------------------------------------------------------------
__global__ __launch_bounds__(256) void convert_all(
    const float* __restrict__ x, __bf16* __restrict__ xb,
    __bf16* __restrict__ xT, const float* __restrict__ wA,
    const float* __restrict__ wB, const float* __restrict__ wV,
    const float* __restrict__ bB, const float* __restrict__ bV,
    __bf16* __restrict__ wAb, __bf16* __restrict__ wBVb,
    float* __restrict__ bBV) {
  if (blockIdx.z == 8) {
    const int t = blockIdx.y * 64 + blockIdx.x;  // 0..511
    const int grp = t >> 7;                      // 128 blocks per matrix
    const int r = t & 127;
    if (grp == 3) {
      if (r == 0) {
#pragma unroll
        for (int j = 0; j < 4; j++) {
          const int i = threadIdx.x * 4 + j;
          bBV[i] = (i < 512) ? bB[i] : bV[i - 512];
        }
      }
      return;
    }
    const float* in = grp == 0 ? wB : (grp == 1 ? wV : wA);
    __bf16* o = grp == 0 ? wBVb : (grp == 1 ? wBVb + 262144 : wAb);
    const long base = (long)r * 2048 + threadIdx.x * 8;  // 2048 elems/block
    float4 v0 = *(const float4*)&in[base];
    float4 v1 = *(const float4*)&in[base + 4];
    bf16x8 ob;
    ob[0] = (__bf16)v0.x; ob[1] = (__bf16)v0.y; ob[2] = (__bf16)v0.z;
    ob[3] = (__bf16)v0.w; ob[4] = (__bf16)v1.x; ob[5] = (__bf16)v1.y;
    ob[6] = (__bf16)v1.z; ob[7] = (__bf16)v1.w;
    *(bf16x8*)&o[base] = ob;
    return;
  }

  __shared__ __bf16 t[64][66];
  const int j0 = blockIdx.x * 64;
  const int c0 = blockIdx.y * 64;
  const long bofs = (long)blockIdx.z * CC * HWN;
  const int j = threadIdx.x & 63;
  const int g = threadIdx.x >> 6;

#pragma unroll
  for (int r = 0; r < 16; r++) {
    const int i = r * 4 + g;
    const float v = x[bofs + (long)(c0 + i) * HWN + j0 + j];
    const __bf16 bv = (__bf16)v;
    xb[bofs + (long)(c0 + i) * HWN + j0 + j] = bv;
    t[j][i] = bv;
  }
  __syncthreads();
#pragma unroll
  for (int r = 0; r < 16; r++) {
    const int jj = r * 4 + g;
    xT[bofs + (long)(j0 + jj) * CC + c0 + j] = t[jj][j];
  }
}

// bf16 transpose: out[b*sOut + j*CC + c] = in[b*sIn + c*ldIn + j]
__global__ __launch_bounds__(256) void transpose_bf16_s(
    const __bf16* __restrict__ in, __bf16* __restrict__ out, int ldIn,
    long sIn, long sOut) {
  __shared__ __bf16 t[64][66];
  const int j0 = blockIdx.x * 64;
  const int c0 = blockIdx.y * 64;
  const int j = threadIdx.x & 63;
  const int g = threadIdx.x >> 6;

#pragma unroll
  for (int r = 0; r < 16; r++) {
    const int i = r * 4 + g;
    t[j][i] = in[(long)blockIdx.z * sIn + (long)(c0 + i) * ldIn + j0 + j];
  }
  __syncthreads();
#pragma unroll
  for (int r = 0; r < 16; r++) {
    const int jj = r * 4 + g;
    out[(long)blockIdx.z * sOut + (long)(j0 + jj) * CC + c0 + j] = t[jj][j];
  }
}

// ---------------------------------------------------------------------------
// Plan:
//  0. convert_all: x->xb,xT; weights->bf16 (stacked wBV); biases packed
//  1. logits = wBV·x + bBV  (M=1024)                -> d_out bf16 [B,1024,HW]
//  2. softmax_dual: B-rows -> bm (ws), V-rows -> in place (av)
//  3. transpose av -> avT into xT region (xT dead)
//  4. M partials split-K=8 (A=bm,B=xb)              -> d_out bf16 (32 MiB)
//  5. reduce -> Mb bf16
//  6. gdT = (wA·M^T + bA)/HW (A=wAb,B=Mb)           -> gdT bf16
//  7. out = gdT·avT          (A=gdT,B=xT)           -> d_out fp32 (full 64MB)
// ---------------------------------------------------------------------------
extern "C" void kernel_launch(void* const* d_in, const int* in_sizes, int n_in,
                              void* d_out, int out_size, void* d_ws,
                              size_t ws_size, hipStream_t stream) {
  const float* x  = (const float*)d_in[0];
  const float* wA = (const float*)d_in[1];
  const float* bA = (const float*)d_in[2];
  const float* wB = (const float*)d_in[3];
  const float* bB = (const float*)d_in[4];
  const float* wV = (const float*)d_in[5];
  const float* bV = (const float*)d_in[6];
  float* out = (float*)d_out;

  const size_t nBCHW = (size_t)BB * CC * HWN;   // 16M
  const size_t nBCC  = (size_t)BB * CC * CC;    // 2M
  __bf16* xb   = (__bf16*)d_ws;          // [B,C,HW]
  __bf16* xT   = xb + nBCHW;             // [B,HW,C]; later avT
  __bf16* bm   = xT + nBCHW;             // [B,C,HW]
  __bf16* Mb   = bm + nBCHW;             // [B,C,C]
  __bf16* gdT  = Mb + nBCC;              // [B,C,C]
  __bf16* wBVb = gdT + nBCC;             // [1024,512]
  __bf16* wAb  = wBVb + (size_t)1024 * CC;
  float*  bBV  = (float*)(wAb + (size_t)CC * CC);  // [1024]

  const long sBC_HW = (long)CC * HWN;    // 2097152
  const long sCC = (long)CC * CC;        // 262144

  convert_all<<<dim3(HWN / 64, CC / 64, BB + 1), 256, 0, stream>>>(
      x, xb, xT, wA, wB, wV, bB, bV, wAb, wBVb, bBV);

  __bf16* logits = (__bf16*)d_out;       // [B,1024,HW] bf16 == 64 MiB

  // 1. merged logits GEMM (M=1024): rows 0-511 B-logits, 512-1023 V-logits
  gemm_mfma_bt<1, __bf16><<<dim3(HWN / 128, 1024 / 128, BB), 256, 0, stream>>>(
      wBVb, xT, bBV, logits, 1024, HWN, CC, 0, sBC_HW, (long)1024 * HWN, 1.0f,
      1, 0);
  // 2. dual softmax
  softmax_dual_bf16<<<dim3(BB * 1024), 256, 0, stream>>>(logits, bm);
  // 3. avT (av rows live at logits + b*4194304 + 2097152 + c*4096)
  transpose_bf16_s<<<dim3(HWN / 64, CC / 64, BB), 256, 0, stream>>>(
      logits + 2097152, xT, HWN, (long)1024 * HWN, (long)HWN * CC);
  // 4. M split-K=8 partials -> d_out as bf16: batch 2097152, slice 262144
  gemm_mfma_bt<0, __bf16><<<dim3(CC / 128, CC / 128, BB * 8), 256, 0,
                            stream>>>(bm, xb, nullptr, (__bf16*)out, CC, CC,
                                      HWN, sBC_HW, sBC_HW, (long)2097152,
                                      1.0f, 8, (long)262144);
  // 5. reduce -> Mb
  reduce_partials8b<<<dim3(1024), 256, 0, stream>>>((const __bf16*)out, Mb);
  // 6. gdT = (wA @ M^T + bA)/HW
  gemm_mfma_bt<1, __bf16><<<dim3(CC / 128, CC / 128, BB), 256, 0, stream>>>(
      wAb, Mb, bA, gdT, CC, CC, CC, 0, sCC, sCC, 1.0f / (float)HWN, 1, 0);
  // 7. out = gdT @ avT -> d_out (fp32, overwrites everything)
  gemm_mfma_bt<0, float><<<dim3(HWN / 128, CC / 128, BB), 256, 0, stream>>>(
      gdT, xT, nullptr, out, CC, HWN, CC, sCC, sBC_HW, sBC_HW, 1.0f, 1, 0);
}